// Round 11
// baseline (239.906 us; speedup 1.0000x reference)
//
#include <hip/hip_runtime.h>
#include <hip/hip_bf16.h>

#define N_NODES 200000
#define KDIM 27
#define C_IN 32
#define C_OUT 32
#define NPART 2
#define PSIZE 100000             // N_NODES/NPART; 6.4 MB bf16 per partition
#define TILES 2                  // tiles (128 nodes each) per block
#define SEGS (TILES * KDIM)      // 54 stages per pass; 54 % PF == 0
#define PF 3                     // frag ring: 48 arch VGPRs (fits ~84 cap @ (256,3))

typedef __bf16 bf16x8 __attribute__((ext_vector_type(8)));
typedef float floatx4 __attribute__((ext_vector_type(4)));
typedef float float4_t __attribute__((ext_vector_type(4)));

__device__ __forceinline__ void load_frag16(bf16x8& dst, const __bf16* addr) {
    asm volatile("global_load_dwordx4 %0, %1, off" : "=v"(dst) : "v"(addr));
}

// ---------------- Kernel 1: fused convert (fp32->bf16 + sentinel) + pack ---
__global__ __launch_bounds__(256) void prep_kernel(
    const float* __restrict__ data, const float* __restrict__ w,
    __bf16* __restrict__ data_bf, __bf16* __restrict__ wpack) {
    const int b = blockIdx.x;
    const int tid = threadIdx.x;
    if (b < 3125) {                       // convert: 3125*256*8 = 6.4M elems
        int i = b * 256 + tid;
        const float4_t* s = (const float4_t*)data;
        float4_t v0 = __builtin_nontemporal_load(&s[2 * i]);
        float4_t v1 = __builtin_nontemporal_load(&s[2 * i + 1]);
        bf16x8 o;
        o[0] = (__bf16)v0[0]; o[1] = (__bf16)v0[1];
        o[2] = (__bf16)v0[2]; o[3] = (__bf16)v0[3];
        o[4] = (__bf16)v1[0]; o[5] = (__bf16)v1[1];
        o[6] = (__bf16)v1[2]; o[7] = (__bf16)v1[3];
        ((bf16x8*)data_bf)[i] = o;
        if (b == 0 && tid < 4) {          // zero sentinel node N_NODES
            bf16x8 z;
#pragma unroll
            for (int t = 0; t < 8; ++t) z[t] = (__bf16)0.0f;
            ((bf16x8*)data_bf)[N_NODES * 4 + tid] = z;
        }
    } else {                              // pack weights: 108 blocks
        int id = (b - 3125) * 256 + tid;
        int j = id & 7;
        int l = (id >> 3) & 63;
        int t = (id >> 9) & 1;
        int kk = id >> 10;
        int c = ((l >> 4) << 3) + j;
        int o = t * 16 + (l & 15);
        wpack[id] = (__bf16)w[(kk * C_IN + c) * C_OUT + o];
    }
}

// ---------------- Kernel 2: persistent soft-synced partition gather-GEMM ---
// R10 result: T = max(traffic/3.2 TB/s, wave_stages * c). NPART=4 minimized
// traffic (FETCH 108 MB) but 885k wave-stages at 2 waves/SIMD made it
// latency-bound (158 us). This version balances: NPART=2 (338k stages,
// fetch ~165 MB), TILES=2 (27.6 KB LDS -> 3 blocks/CU at (256,3), 1.5x
// latency hiding), PF=3 ring (48 regs, fits the ~84 arch-VGPR cap measured
// at (256,3); spill tripwire = WRITE_SIZE). 782 blocks, 768 co-resident
// (1.8% stragglers -> negligible drift). Out-of-partition taps read the
// L1-hot zero sentinel (exact: fp32 acc + 0.0). Uniform vmcnt(8): 12 loads
// in flight (3 stages x 4), retire oldest stage's 4; issue runs
// continuously across pass boundaries (stages 51-53 issue next pass's 0-2,
// last pass's are all-sentinel phantoms drained by the final vmcnt(0)).

#define MFMA4(S, CT)                                                            \
    acc00[CT] = __builtin_amdgcn_mfma_f32_16x16x32_bf16(a0b[S], b0b[S], acc00[CT], 0, 0, 0); \
    acc01[CT] = __builtin_amdgcn_mfma_f32_16x16x32_bf16(a0b[S], b1b[S], acc01[CT], 0, 0, 0); \
    acc10[CT] = __builtin_amdgcn_mfma_f32_16x16x32_bf16(a1b[S], b0b[S], acc10[CT], 0, 0, 0); \
    acc11[CT] = __builtin_amdgcn_mfma_f32_16x16x32_bf16(a1b[S], b1b[S], acc11[CT], 0, 0, 0);

#define STAGE(J)                                                                \
    {                                                                           \
        asm volatile("s_waitcnt vmcnt(8)" ::: "memory");                        \
        __builtin_amdgcn_sched_barrier(0);                                      \
        constexpr int s_  = (J) % PF;                                           \
        constexpr int ct_ = (J) / KDIM;            /* consume tile for acc */   \
        MFMA4(s_, ct_)                                                          \
        {                                                                       \
            constexpr int T_  = (J) + PF;          /* issue target stage  */    \
            constexpr int kT_ = T_ % KDIM;                                      \
            const int lo_ = (T_ < SEGS) ? lo_cur : lo_next;                     \
            int raw0_ = rp0[(J) % 3];                                           \
            int raw1_ = rp1[(J) % 3];                                           \
            unsigned u0_ = ((unsigned)raw0_ - (unsigned)lo_ < (unsigned)PSIZE)  \
                               ? (unsigned)raw0_ : (unsigned)N_NODES;           \
            unsigned u1_ = ((unsigned)raw1_ - (unsigned)lo_ < (unsigned)PSIZE)  \
                               ? (unsigned)raw1_ : (unsigned)N_NODES;           \
            load_frag16(a0b[s_], dch + ((size_t)u0_ << 5));                     \
            load_frag16(a1b[s_], dch + ((size_t)u1_ << 5));                     \
            load_frag16(b0b[s_], wlane + kT_ * 1024);                           \
            load_frag16(b1b[s_], wlane + kT_ * 1024 + 512);                     \
        }                                                                       \
        {                                                                       \
            constexpr int T2_ = ((J) + PF + 2) % SEGS; /* idx for stage J+2 */  \
            constexpr int t2_ = T2_ / KDIM, k2_ = T2_ % KDIM;                   \
            rp0[((J) + 2) % 3] = nlds[t2_ * 3456 + rA0 + k2_];                  \
            rp1[((J) + 2) % 3] = nlds[t2_ * 3456 + rA0 + 432 + k2_];            \
        }                                                                       \
    }

#define S9(a) STAGE(a) STAGE((a)+1) STAGE((a)+2) STAGE((a)+3) STAGE((a)+4) \
              STAGE((a)+5) STAGE((a)+6) STAGE((a)+7) STAGE((a)+8)

#define PRIME(T)                                                                \
    {                                                                           \
        int q0 = nlds[rA0 + (T)];                                               \
        int q1 = nlds[rA0 + 432 + (T)];                                         \
        unsigned u0_ = ((unsigned)q0 < (unsigned)PSIZE) ? (unsigned)q0          \
                                                        : (unsigned)N_NODES;    \
        unsigned u1_ = ((unsigned)q1 < (unsigned)PSIZE) ? (unsigned)q1          \
                                                        : (unsigned)N_NODES;    \
        load_frag16(a0b[(T)], dch + ((size_t)u0_ << 5));                        \
        load_frag16(a1b[(T)], dch + ((size_t)u1_ << 5));                        \
        load_frag16(b0b[(T)], wlane + (T) * 1024);                              \
        load_frag16(b1b[(T)], wlane + (T) * 1024 + 512);                        \
    }

__global__ __launch_bounds__(256, 3) void octconv_main_kernel(
    const int* __restrict__ neigh, const __bf16* __restrict__ data_bf,
    const __bf16* __restrict__ wpack, float* __restrict__ out) {
    __shared__ int nlds[TILES * 128 * KDIM];   // 27648 B: 2 tile slabs

    const int tid  = threadIdx.x;
    const int wave = tid >> 6;
    const int lane = tid & 63;
    const int r16  = lane & 15;
    const int half = lane >> 4;
    const int cb   = half << 3;

    // stage this block's 2 tiles' neigh -> LDS once (contiguous, coalesced)
    {
        const long long gbase = (long long)blockIdx.x * (TILES * 128 * KDIM);
        const long long gmax  = (long long)N_NODES * KDIM;
#pragma unroll 1
        for (int i = tid; i < TILES * 128 * KDIM; i += 256) {
            long long gg = gbase + i;
            nlds[i] = (gg < gmax) ? __builtin_nontemporal_load(&neigh[gg]) : -1;
        }
    }
    __syncthreads();

    const int rA0 = (wave * 32 + r16) * KDIM;    // row base within a tile slab
    const __bf16* dch   = data_bf + cb;
    const __bf16* wlane = wpack + (size_t)lane * 8;

    floatx4 acc00[TILES], acc01[TILES], acc10[TILES], acc11[TILES];
#pragma unroll
    for (int t = 0; t < TILES; ++t) {
        acc00[t] = floatx4{0.f, 0.f, 0.f, 0.f};
        acc01[t] = floatx4{0.f, 0.f, 0.f, 0.f};
        acc10[t] = floatx4{0.f, 0.f, 0.f, 0.f};
        acc11[t] = floatx4{0.f, 0.f, 0.f, 0.f};
    }

    bf16x8 a0b[PF], a1b[PF], b0b[PF], b1b[PF];   // asm-pinned frag ring
    int rp0[3], rp1[3];                          // idx ring, 2-stage lead

    // prologue (pass 0, lo=0): issue targets 0..2 (tile 0), prime idx ring
    PRIME(0) PRIME(1) PRIME(2)
    rp0[0] = nlds[rA0 + 3]; rp1[0] = nlds[rA0 + 432 + 3];   // for target 3
    rp0[1] = nlds[rA0 + 4]; rp1[1] = nlds[rA0 + 432 + 4];   // for target 4

    int lo_cur = 0, lo_next = PSIZE;
#pragma unroll 1
    for (int p = 0; p < NPART; ++p) {
        S9(0) S9(9) S9(18) S9(27) S9(36) S9(45)
        lo_cur += PSIZE;
        lo_next += PSIZE;
    }

    asm volatile("s_waitcnt vmcnt(0)" ::: "memory");  // drain phantom issues
    __builtin_amdgcn_sched_barrier(0);

#pragma unroll
    for (int t = 0; t < TILES; ++t) {
        const int node_base = (blockIdx.x * TILES + t) * 128 + wave * 32;
#pragma unroll
        for (int r = 0; r < 4; ++r) {
            int n0 = node_base + half * 4 + r;
            int n1 = n0 + 16;
            if (n0 < N_NODES) {
                __builtin_nontemporal_store(acc00[t][r], &out[n0 * C_OUT + r16]);
                __builtin_nontemporal_store(acc01[t][r], &out[n0 * C_OUT + 16 + r16]);
            }
            if (n1 < N_NODES) {
                __builtin_nontemporal_store(acc10[t][r], &out[n1 * C_OUT + r16]);
                __builtin_nontemporal_store(acc11[t][r], &out[n1 * C_OUT + 16 + r16]);
            }
        }
    }
}

extern "C" void kernel_launch(void* const* d_in, const int* in_sizes, int n_in,
                              void* d_out, int out_size, void* d_ws, size_t ws_size,
                              hipStream_t stream) {
    const float* data    = (const float*)d_in[0];   // [N, C_IN] fp32
    const float* weights = (const float*)d_in[1];   // [K, C_IN, C_OUT] fp32
    const int*   neigh   = (const int*)d_in[2];     // [N, K] int32
    float*       out     = (float*)d_out;           // [N, C_OUT] fp32

    __bf16* data_bf = (__bf16*)d_ws;
    __bf16* wpack   = (__bf16*)((char*)d_ws + (size_t)(N_NODES + 1) * C_IN * sizeof(__bf16));

    // 1) fused convert + sentinel + weight pack
    hipLaunchKernelGGL(prep_kernel, dim3(3125 + 108), dim3(256), 0, stream,
                       data, weights, data_bf, wpack);

    // 2) persistent soft-synced partitioned gather-GEMM: 782 blocks
    //    (3/CU -> 768 co-resident, 14 stragglers = 1.8%)
    int blocks = (N_NODES + TILES * 128 - 1) / (TILES * 128);   // 782
    hipLaunchKernelGGL(octconv_main_kernel, dim3(blocks), dim3(256), 0, stream,
                       neigh, data_bf, wpack, out);
}

// Round 13
// 172.293 us; speedup vs baseline: 1.3924x; 1.3924x over previous
//
#include <hip/hip_runtime.h>
#include <hip/hip_bf16.h>

#define N_NODES 200000
#define KDIM 27
#define C_IN 32
#define C_OUT 32
#define NPART 2
#define PSIZE 100000             // N_NODES/NPART; 6.4 MB bf16 per partition
#define TILES 2                  // tiles (128 nodes each) per block
#define SEGS (TILES * KDIM)      // 54 stages per pass

typedef __bf16 bf16x8 __attribute__((ext_vector_type(8)));
typedef float floatx4 __attribute__((ext_vector_type(4)));
typedef float float4_t __attribute__((ext_vector_type(4)));

// saddr-form loads: 32-bit VGPR offset + SGPR base (saves ~6 VGPR vs 64-bit vaddr)
__device__ __forceinline__ void load_a(bf16x8& dst, unsigned voff, const __bf16* base) {
    asm volatile("global_load_dwordx4 %0, %1, %2" : "=v"(dst) : "v"(voff), "s"(base));
}
__device__ __forceinline__ void load_b0(bf16x8& dst, unsigned voff, const __bf16* base) {
    asm volatile("global_load_dwordx4 %0, %1, %2" : "=v"(dst) : "v"(voff), "s"(base));
}
__device__ __forceinline__ void load_b1(bf16x8& dst, unsigned voff, const __bf16* base) {
    asm volatile("global_load_dwordx4 %0, %1, %2 offset:1024" : "=v"(dst) : "v"(voff), "s"(base));
}

// ---------------- Kernel 1: fused convert (fp32->bf16 + sentinel) + pack ---
__global__ __launch_bounds__(256) void prep_kernel(
    const float* __restrict__ data, const float* __restrict__ w,
    __bf16* __restrict__ data_bf, __bf16* __restrict__ wpack) {
    const int b = blockIdx.x;
    const int tid = threadIdx.x;
    if (b < 3125) {                       // convert: 3125*256*8 = 6.4M elems
        int i = b * 256 + tid;
        const float4_t* s = (const float4_t*)data;
        float4_t v0 = __builtin_nontemporal_load(&s[2 * i]);
        float4_t v1 = __builtin_nontemporal_load(&s[2 * i + 1]);
        bf16x8 o;
        o[0] = (__bf16)v0[0]; o[1] = (__bf16)v0[1];
        o[2] = (__bf16)v0[2]; o[3] = (__bf16)v0[3];
        o[4] = (__bf16)v1[0]; o[5] = (__bf16)v1[1];
        o[6] = (__bf16)v1[2]; o[7] = (__bf16)v1[3];
        ((bf16x8*)data_bf)[i] = o;
        if (b == 0 && tid < 4) {          // zero sentinel node N_NODES
            bf16x8 z;
#pragma unroll
            for (int t = 0; t < 8; ++t) z[t] = (__bf16)0.0f;
            ((bf16x8*)data_bf)[N_NODES * 4 + tid] = z;
        }
    } else {                              // pack weights: 108 blocks
        int id = (b - 3125) * 256 + tid;
        int j = id & 7;
        int l = (id >> 3) & 63;
        int t = (id >> 9) & 1;
        int kk = id >> 10;
        int c = ((l >> 4) << 3) + j;
        int o = t * 16 + (l & 15);
        wpack[id] = (__bf16)w[(kk * C_IN + c) * C_OUT + o];
    }
}

// ---------------- Kernel 2: partitioned gather-GEMM, register-dieted -------
// T = max(traffic/3.2TB/s, latency term). NPART=2 target: ~178 MB -> 56 us,
// needs 3 waves/SIMD ((256,3), arch cap 84). R11 spilled at ~90 live regs;
// this version cuts to ~75: (1) B-hoist - B-frags are tap-only, loaded once
// per tap into a mod-3 buffer (WAR-safe; 27%3==0 wraps cleanly), pair issued
// on even stages; (2) saddr-form gathers (32-bit voffset + SGPR base);
// (3) alternating counted waits vmcnt(6)/(8) (even/odd), ledger-verified.
// Stage j: tile t=j&1, tap kk=j>>1; A-slot j%3 (target T=j+3 -> same slot);
// idx ring rp[3] read from LDS 2 stages ahead. Out-of-partition taps read
// the zero sentinel (exact). Phantom tail issues drain via final vmcnt(0).

#define MFMA4(SA, SB, CT)                                                       \
    acc00[CT] = __builtin_amdgcn_mfma_f32_16x16x32_bf16(a0b[SA], b0b[SB], acc00[CT], 0, 0, 0); \
    acc01[CT] = __builtin_amdgcn_mfma_f32_16x16x32_bf16(a0b[SA], b1b[SB], acc01[CT], 0, 0, 0); \
    acc10[CT] = __builtin_amdgcn_mfma_f32_16x16x32_bf16(a1b[SA], b0b[SB], acc10[CT], 0, 0, 0); \
    acc11[CT] = __builtin_amdgcn_mfma_f32_16x16x32_bf16(a1b[SA], b1b[SB], acc11[CT], 0, 0, 0);

#define STAGE(J)                                                                \
    {                                                                           \
        asm volatile("s_waitcnt vmcnt(%0)" ::"n"(((J) & 1) ? 8 : 6) : "memory");\
        __builtin_amdgcn_sched_barrier(0);                                      \
        constexpr int t_  = (J) & 1;                                            \
        constexpr int kk_ = (J) >> 1;                                           \
        constexpr int sa_ = (J) % 3;                                            \
        constexpr int sb_ = kk_ % 3;                                            \
        MFMA4(sa_, sb_, t_)                                                     \
        {   /* A issue for target T = J+3 (slot T%3 == sa_) */                  \
            constexpr int T_ = (J) + 3;                                         \
            const int lo_ = (T_ < SEGS) ? lo_cur : lo_next;                     \
            int r0_ = rp0[(J) % 3], r1_ = rp1[(J) % 3];                         \
            unsigned u0_ = ((unsigned)(r0_ - lo_) < (unsigned)PSIZE)            \
                               ? (unsigned)r0_ : (unsigned)N_NODES;             \
            unsigned u1_ = ((unsigned)(r1_ - lo_) < (unsigned)PSIZE)            \
                               ? (unsigned)r1_ : (unsigned)N_NODES;             \
            load_a(a0b[sa_], (u0_ << 6) + cboff, data_bf);                      \
            load_a(a1b[sa_], (u1_ << 6) + cboff, data_bf);                      \
        }                                                                       \
        if constexpr (t_ == 0) { /* B pair for tap kk+2 (mod 27), buf mod 3 */  \
            constexpr int kb_ = (kk_ + 2) % KDIM;                               \
            constexpr int bs_ = (kk_ + 2) % 3;                                  \
            unsigned vb_ = vlane16 + kb_ * 2048;                                \
            load_b0(b0b[bs_], vb_, wpack);                                      \
            load_b1(b1b[bs_], vb_, wpack);                                      \
        }                                                                       \
        {   /* idx prefetch for stage J+2 (target T2 = J+5, pass-invariant) */  \
            constexpr int TT2_ = ((J) + 5) % SEGS;                              \
            constexpr int t2_ = TT2_ & 1, k2_ = TT2_ >> 1;                      \
            rp0[((J) + 2) % 3] = nlds[t2_ * 3456 + rA0 + k2_];                  \
            rp1[((J) + 2) % 3] = nlds[t2_ * 3456 + rA0 + 432 + k2_];            \
        }                                                                       \
    }

#define S9(a) STAGE(a) STAGE((a)+1) STAGE((a)+2) STAGE((a)+3) STAGE((a)+4) \
              STAGE((a)+5) STAGE((a)+6) STAGE((a)+7) STAGE((a)+8)

// prologue A for target T (pass 0, lo=0): tile T&1, tap T>>1, slot T%3
#define PRIME_A(T)                                                              \
    {                                                                           \
        int q0_ = nlds[((T) & 1) * 3456 + rA0 + ((T) >> 1)];                    \
        int q1_ = nlds[((T) & 1) * 3456 + rA0 + 432 + ((T) >> 1)];              \
        unsigned u0_ = ((unsigned)q0_ < (unsigned)PSIZE) ? (unsigned)q0_        \
                                                         : (unsigned)N_NODES;   \
        unsigned u1_ = ((unsigned)q1_ < (unsigned)PSIZE) ? (unsigned)q1_        \
                                                         : (unsigned)N_NODES;   \
        load_a(a0b[(T) % 3], (u0_ << 6) + cboff, data_bf);                      \
        load_a(a1b[(T) % 3], (u1_ << 6) + cboff, data_bf);                      \
    }
#define PRIME_B(K)                                                              \
    {                                                                           \
        unsigned vb_ = vlane16 + (K) * 2048;                                    \
        load_b0(b0b[(K) % 3], vb_, wpack);                                      \
        load_b1(b1b[(K) % 3], vb_, wpack);                                      \
    }

__global__ __launch_bounds__(256, 3) void octconv_main_kernel(
    const int* __restrict__ neigh, const __bf16* __restrict__ data_bf,
    const __bf16* __restrict__ wpack, float* __restrict__ out) {
    __shared__ int nlds[TILES * 128 * KDIM];   // 27648 B: 2 tile slabs

    const int tid  = threadIdx.x;
    const int wave = tid >> 6;
    const int lane = tid & 63;
    const int r16  = lane & 15;
    const int half = lane >> 4;

    // stage neigh -> LDS once, coalesced
    {
        const long long gbase = (long long)blockIdx.x * (TILES * 128 * KDIM);
        const long long gmax  = (long long)N_NODES * KDIM;
#pragma unroll 1
        for (int i = tid; i < TILES * 128 * KDIM; i += 256) {
            long long gg = gbase + i;
            nlds[i] = (gg < gmax) ? __builtin_nontemporal_load(&neigh[gg]) : -1;
        }
    }
    __syncthreads();

    const int rA0 = (wave * 32 + r16) * KDIM;     // row base within tile slab
    const unsigned cboff   = (unsigned)(half << 4);  // channel byte offset
    const unsigned vlane16 = (unsigned)(lane << 4);  // B-frag lane byte offset

    floatx4 acc00[TILES], acc01[TILES], acc10[TILES], acc11[TILES];
#pragma unroll
    for (int t = 0; t < TILES; ++t) {
        acc00[t] = floatx4{0.f, 0.f, 0.f, 0.f};
        acc01[t] = floatx4{0.f, 0.f, 0.f, 0.f};
        acc10[t] = floatx4{0.f, 0.f, 0.f, 0.f};
        acc11[t] = floatx4{0.f, 0.f, 0.f, 0.f};
    }

    bf16x8 a0b[3], a1b[3];        // A ring (24 VGPR)
    bf16x8 b0b[3], b1b[3];        // B tap-buffers (24 VGPR)
    int rp0[3], rp1[3];           // idx ring, 2-stage lead

    // prologue order [A0,B0,A1,B1,A2]: ledger-verified vs vmcnt(6)/(8)
    PRIME_A(0) PRIME_B(0) PRIME_A(1) PRIME_B(1) PRIME_A(2)
    rp0[0] = nlds[3456 + rA0 + 1];       rp1[0] = nlds[3456 + rA0 + 432 + 1];  // T=3
    rp0[1] = nlds[rA0 + 2];              rp1[1] = nlds[rA0 + 432 + 2];         // T=4

    int lo_cur = 0, lo_next = PSIZE;
#pragma unroll 1
    for (int p = 0; p < NPART; ++p) {
        S9(0) S9(9) S9(18) S9(27) S9(36) S9(45)
        lo_cur += PSIZE;
        lo_next += PSIZE;
    }

    asm volatile("s_waitcnt vmcnt(0)" ::: "memory");  // drain phantom issues
    __builtin_amdgcn_sched_barrier(0);

#pragma unroll
    for (int t = 0; t < TILES; ++t) {
        const int node_base = (blockIdx.x * TILES + t) * 128 + wave * 32;
#pragma unroll
        for (int r = 0; r < 4; ++r) {
            int n0 = node_base + half * 4 + r;
            int n1 = n0 + 16;
            if (n0 < N_NODES) {
                __builtin_nontemporal_store(acc00[t][r], &out[n0 * C_OUT + r16]);
                __builtin_nontemporal_store(acc01[t][r], &out[n0 * C_OUT + 16 + r16]);
            }
            if (n1 < N_NODES) {
                __builtin_nontemporal_store(acc10[t][r], &out[n1 * C_OUT + r16]);
                __builtin_nontemporal_store(acc11[t][r], &out[n1 * C_OUT + 16 + r16]);
            }
        }
    }
}

extern "C" void kernel_launch(void* const* d_in, const int* in_sizes, int n_in,
                              void* d_out, int out_size, void* d_ws, size_t ws_size,
                              hipStream_t stream) {
    const float* data    = (const float*)d_in[0];   // [N, C_IN] fp32
    const float* weights = (const float*)d_in[1];   // [K, C_IN, C_OUT] fp32
    const int*   neigh   = (const int*)d_in[2];     // [N, K] int32
    float*       out     = (float*)d_out;           // [N, C_OUT] fp32

    __bf16* data_bf = (__bf16*)d_ws;
    __bf16* wpack   = (__bf16*)((char*)d_ws + (size_t)(N_NODES + 1) * C_IN * sizeof(__bf16));

    // 1) fused convert + sentinel + weight pack
    hipLaunchKernelGGL(prep_kernel, dim3(3125 + 108), dim3(256), 0, stream,
                       data, weights, data_bf, wpack);

    // 2) partitioned gather-GEMM: 782 blocks, 3/CU -> ~768 co-resident
    int blocks = (N_NODES + TILES * 128 - 1) / (TILES * 128);   // 782
    hipLaunchKernelGGL(octconv_main_kernel, dim3(blocks), dim3(256), 0, stream,
                       neigh, data_bf, wpack, out);
}